// Round 4
// baseline (188.173 us; speedup 1.0000x reference)
//
#include <hip/hip_runtime.h>
#include <hip/hip_bf16.h>

// R11: R10 (8-wave / 512-thread attn blocks, wave = 16-row slab x 32-key
// half) with the spill fixed: __launch_bounds__(512, 2) instead of (512, 4).
// R10's (512,4) made the compiler cap at 64 VGPR (8 waves/SIMD target) ->
// ~14 MB scratch writes per dispatch, dur 80us. (512,2) allows >=128 VGPR
// per wave under either launch-bounds interpretation; per-wave demand ~110
// fits -> no spill, 2 blocks/CU x 8 waves = 4 waves/SIMD occupancy retained.
// Everything else identical to R10.

#define B_    16
#define LQ_   2048
#define LK_   2048
#define DIM_  128
#define NTH   256
#define ATH   512
#define SCALE_ 0.08838834764831845f          // 1/sqrt(128)
#define LOG2E_ 1.4426950408889634f
#define SC2_   (SCALE_ * LOG2E_)
#define NEGBIG -1.0e9f
#define PS 72                                 // sP row stride (ushorts)

typedef __attribute__((ext_vector_type(8))) short bf16x8;
typedef __attribute__((ext_vector_type(4))) float f32x4;

#define GLDS(gsrc, ldst) \
  __builtin_amdgcn_global_load_lds( \
      (const __attribute__((address_space(1))) unsigned int*)(gsrc), \
      (__attribute__((address_space(3))) unsigned int*)(ldst), 16, 0, 0)

#define MFMA16(A, Bv, C) __builtin_amdgcn_mfma_f32_16x16x32_bf16((A), (Bv), (C), 0, 0, 0)

static __device__ __forceinline__ unsigned short f2bf(float f) {
    unsigned int u = __builtin_bit_cast(unsigned int, f);
    u += 0x7fff + ((u >> 16) & 1);          // RNE
    return (unsigned short)(u >> 16);
}

// ---- kernel 1: kept-key index list (mask==0 kept), 1 block ----
__global__ __launch_bounds__(256) void build_idx(const float* __restrict__ Mk,
                                                 int* __restrict__ hdr,
                                                 int* __restrict__ idx)
{
    __shared__ int sc[256];
    int t = threadIdx.x;
    int keep[8], loc[8];
    int c = 0;
    #pragma unroll
    for (int j = 0; j < 8; ++j) {
        keep[j] = (Mk[t * 8 + j] < 0.5f) ? 1 : 0;
        loc[j] = c;
        c += keep[j];
    }
    sc[t] = c;
    __syncthreads();
    for (int off = 1; off < 256; off <<= 1) {
        int v = (t >= off) ? sc[t - off] : 0;
        __syncthreads();
        sc[t] += v;
        __syncthreads();
    }
    int base = sc[t] - c;
    #pragma unroll
    for (int j = 0; j < 8; ++j)
        if (keep[j]) idx[base + loc[j]] = t * 8 + j;
    if (t == 255) hdr[0] = sc[255];
}

// ---- kernel 2: gather-pack kept K rows (key-interleaved, chunk^row swizzle)
//      + V^T tiles: layout off = kc*4096 + d*32 + (c&3)*8 (kc = key-half),
//      so PV frag (16 rows x 16B) is 1KB contiguous per instruction. ----
__global__ __launch_bounds__(NTH) void pack_kv(
    const float* __restrict__ K, const float* __restrict__ V,
    const int* __restrict__ hdr, const int* __restrict__ idx,
    unsigned short* __restrict__ Kb, unsigned short* __restrict__ Vtb)
{
    const int cnt = hdr[0];
    int bid = blockIdx.x;
    if (bid < 2048) {
        int gid = bid * NTH + threadIdx.x;     // granule = 8 floats (1 chunk)
        int c  = gid & 15;
        int r2 = (gid >> 4) & 63;              // packed (interleaved) row
        int T  = gid >> 10;                    // batch*32 + tile
        int slot = (r2 & 32) + 2 * (r2 & 15) + ((r2 >> 4) & 1);
        int j = (T & 31) * 64 + slot;
        int key = (j < cnt) ? idx[j] : 0;
        const float4* s4 = (const float4*)(K + ((size_t)(T >> 5) * LK_ + key) * DIM_ + c * 8);
        float4 a = s4[0], bq = s4[1];
        bf16x8 h = { (short)f2bf(a.x),  (short)f2bf(a.y),  (short)f2bf(a.z),  (short)f2bf(a.w),
                     (short)f2bf(bq.x), (short)f2bf(bq.y), (short)f2bf(bq.z), (short)f2bf(bq.w) };
        *(bf16x8*)(Kb + (size_t)T * 8192 + r2 * 128 + ((c ^ (r2 & 15)) * 8)) = h;
    } else {
        int T = bid - 2048;                    // batch*32 + tile
        int w4 = threadIdx.x >> 6, lane = threadIdx.x & 63;
        const float* vb = V + (size_t)(T >> 5) * LK_ * DIM_;
        const int* ix = idx + (T & 31) * 64;
        int jbase = (T & 31) * 64;
        unsigned short* db = Vtb + (size_t)T * 8192;
        #pragma unroll
        for (int half = 0; half < 2; ++half) {
            int d = half * 64 + lane;
            #pragma unroll
            for (int cb = 0; cb < 8; cb += 4) {
                int c = cb + w4;               // chunk of 8 keys, c in 0..7
                float v[8];
                #pragma unroll
                for (int kk = 0; kk < 8; ++kk) {
                    int j = c * 8 + kk;
                    int key = (jbase + j < cnt) ? ix[j] : 0;
                    v[kk] = vb[(size_t)key * DIM_ + d];   // coalesced over lanes (d)
                }
                bf16x8 h = { (short)f2bf(v[0]), (short)f2bf(v[1]), (short)f2bf(v[2]), (short)f2bf(v[3]),
                             (short)f2bf(v[4]), (short)f2bf(v[5]), (short)f2bf(v[6]), (short)f2bf(v[7]) };
                *(bf16x8*)(db + (c >> 2) * 4096 + d * 32 + (c & 3) * 8) = h;
            }
        }
    }
}

// ---- main kernel: 8 waves, wave = 16-row slab x 32-key half ----
__global__ __launch_bounds__(ATH, 2) void attn_mfma8(
    const float* __restrict__ Q, const unsigned short* __restrict__ Kb,
    const unsigned short* __restrict__ Vtb, const int* __restrict__ hdr,
    float* __restrict__ O)
{
    __shared__ __align__(16) unsigned short sKa[8192];     // 16 KB
    __shared__ __align__(16) unsigned short sKb_[8192];    // 16 KB
    __shared__ __align__(16) unsigned short sP[64 * PS];   // 9.2 KB, also Q staging
    __shared__ float sLp[64];

    const int tid  = threadIdx.x;
    const int w    = tid >> 6, lane = tid & 63;
    const int quad = lane >> 4, l15 = lane & 15;
    const int rg   = (w & 3) * 16;     // row slab base: 0/16/32/48
    const int wh   = w >> 2;           // key half
    const int kh   = wh * 32;

    const int bid = blockIdx.x;
    const int grp = bid >> 3;
    const int b   = (bid & 7) + 8 * (grp & 1);   // XCD-aware
    const int q0  = (grp >> 1) * 64;

    const int cnt = hdr[0];
    const int n = (((cnt + 63) >> 6) + 1) & ~1;   // even # of 64-key tiles (>=2)

    bf16x8 vone;
    #pragma unroll
    for (int j = 0; j < 8; ++j) vone[j] = (short)0x3F80;

    // per-lane V-frag base offset (ushorts) within a tile
    const int voff = wh * 4096 + l15 * 32 + quad * 8;
    const unsigned short* vtb = Vtb + (size_t)(b * 32) * 8192 + voff;

    const char* kbase = (const char*)Kb + (size_t)(b * 32) * 16384;

    // ---- issue K0 prefetch FIRST (overlaps Q staging; drained by its barriers)
    #pragma unroll
    for (int j = 0; j < 2; ++j) {
        int o = (j * 8 + w) * 1024;
        GLDS(kbase + o + lane * 16, (char*)sKa + o);
    }

    // ---- stage Q (pre-scaled by SC2_) in two 32-row halves through sP ----
    bf16x8 aQ[4];
    {
        const float4* Qg = (const float4*)(Q + ((size_t)b * LQ_ + q0) * DIM_);
        #pragma unroll
        for (int h = 0; h < 2; ++h) {
            #pragma unroll
            for (int it = 0; it < 2; ++it) {
                int i2 = tid + it * ATH;
                int r = i2 >> 5, c4 = i2 & 31;
                float4 v = Qg[(h * 32 + r) * 32 + c4];
                ushort4 hh = { f2bf(v.x * SC2_), f2bf(v.y * SC2_),
                               f2bf(v.z * SC2_), f2bf(v.w * SC2_) };
                *(ushort4*)&sP[r * 128 + (((c4 >> 1) ^ (r & 15)) * 8) + (c4 & 1) * 4] = hh;
            }
            __syncthreads();
            if ((rg >> 5) == h) {
                #pragma unroll
                for (int ks = 0; ks < 4; ++ks)
                    aQ[ks] = *(const bf16x8*)&sP[((rg & 16) + l15) * 128 +
                                                 (((ks * 4 + quad) ^ l15) * 8)];
            }
            __syncthreads();
        }
    }
    // K0 GLDS is complete for ALL waves here (barriers drain vmcnt).

    f32x4 acc[8], lacc;
    lacc = (f32x4){0.f, 0.f, 0.f, 0.f};
    #pragma unroll
    for (int dt = 0; dt < 8; ++dt) acc[dt] = (f32x4){0.f, 0.f, 0.f, 0.f};

    f32x4 s_[2];    // raw scores for the "current" tile, carried across iters

// QK for one tile from LDS buffer RD -> s_ (2 independent MFMA chains)
#define QK_TILE(RD) do {                                                       \
    f32x4 c0 = (f32x4){0.f,0.f,0.f,0.f};                                       \
    f32x4 c1 = (f32x4){0.f,0.f,0.f,0.f};                                       \
    _Pragma("unroll")                                                          \
    for (int ks = 0; ks < 4; ++ks) {                                           \
        int co = ((ks * 4 + quad) ^ l15) * 8;                                  \
        bf16x8 bk0 = *(const bf16x8*)&(RD)[(kh + l15) * 128 + co];             \
        bf16x8 bk1 = *(const bf16x8*)&(RD)[(kh + 16 + l15) * 128 + co];        \
        c0 = MFMA16(aQ[ks], bk0, c0);                                          \
        c1 = MFMA16(aQ[ks], bk1, c1);                                          \
    }                                                                          \
    s_[0] = c0; s_[1] = c1;                                                    \
} while (0)

// softmax on current s_ (tile TI) -> sP (wave-local rows) -> aP
// mask applied post-exp2 via AND on the packed bf16 pair
#define SOFTMAX_AP(TI) do {                                                    \
    int slot0 = (TI) * 64 + kh + 2 * l15;                                      \
    unsigned umask = (slot0     < cnt ? 0x0000FFFFu : 0u) |                    \
                     (slot0 + 1 < cnt ? 0xFFFF0000u : 0u);                     \
    _Pragma("unroll")                                                          \
    for (int r = 0; r < 4; ++r) {                                              \
        float p0 = __builtin_amdgcn_exp2f(s_[0][r]);                           \
        float p1 = __builtin_amdgcn_exp2f(s_[1][r]);                           \
        int row = rg + quad * 4 + r;                                           \
        unsigned pk = __builtin_amdgcn_perm(                                   \
            __builtin_bit_cast(unsigned, p1),                                  \
            __builtin_bit_cast(unsigned, p0), 0x07060302u) & umask;            \
        *(unsigned*)&sP[row * PS + kh + 2 * l15] = pk;                         \
    }                                                                          \
    aP = *(const bf16x8*)&sP[(rg + l15) * PS + kh + quad * 8];                 \
} while (0)

// pipelined tile body:
//   barrier; load bv(I) (issued before GLDS); GLDS K(I+2)->WR;
//   softmax(I); QK(I+1) || PV(I)
#define BODY(RD, WR, I) do {                                                   \
    __syncthreads();   /* K(I+1) staged; WR free (last read: QK(I)) */         \
    const unsigned short* vsrc = vtb + (size_t)(I) * 8192;                     \
    bf16x8 bv[8];                                                              \
    _Pragma("unroll")                                                          \
    for (int dt = 0; dt < 8; ++dt) bv[dt] = *(const bf16x8*)(vsrc + dt * 512); \
    {                                                                          \
        int t2 = (I) + 2; if (t2 > n - 1) t2 = n - 1;                          \
        const char* ksrc = kbase + (size_t)t2 * 16384;                         \
        _Pragma("unroll")                                                      \
        for (int j = 0; j < 2; ++j) {                                          \
            int o = (j * 8 + w) * 1024;                                        \
            GLDS(ksrc + o + lane * 16, (char*)(WR) + o);                       \
        }                                                                      \
    }                                                                          \
    bf16x8 aP;                                                                 \
    SOFTMAX_AP(I);                                                             \
    __builtin_amdgcn_s_setprio(1);                                             \
    QK_TILE(RD);               /* scores for tile I+1 */                       \
    lacc = MFMA16(aP, vone, lacc);                                             \
    _Pragma("unroll")                                                          \
    for (int dt = 0; dt < 8; ++dt)                                             \
        acc[dt] = MFMA16(aP, bv[dt], acc[dt]);                                 \
    __builtin_amdgcn_s_setprio(0);                                             \
} while (0)

    // ---- prologue: issue GLDS K1 -> sKb_, then QK(0) from sKa ----
    {
        const char* ksrc = kbase + 16384;
        #pragma unroll
        for (int j = 0; j < 2; ++j) {
            int o = (j * 8 + w) * 1024;
            GLDS(ksrc + o + lane * 16, (char*)sKb_ + o);
        }
    }
    QK_TILE(sKa);

    // ---- main loop: n-1 pipelined bodies (odd count), constant LDS names ----
    int i = 0;
    for (; i + 1 < n - 1; i += 2) {
        BODY(sKb_, sKa, i);
        BODY(sKa, sKb_, i + 1);
    }
    if (i < n - 1) BODY(sKb_, sKa, i);

    // ---- tail: softmax + PV for tile n-1 (no K access, no barrier) ----
    {
        const unsigned short* vsrc = vtb + (size_t)(n - 1) * 8192;
        bf16x8 bv[8];
        #pragma unroll
        for (int dt = 0; dt < 8; ++dt) bv[dt] = *(const bf16x8*)(vsrc + dt * 512);
        bf16x8 aP;
        SOFTMAX_AP(n - 1);
        lacc = MFMA16(aP, vone, lacc);
        #pragma unroll
        for (int dt = 0; dt < 8; ++dt)
            acc[dt] = MFMA16(aP, bv[dt], acc[dt]);
    }
#undef BODY
#undef SOFTMAX_AP
#undef QK_TILE

    __syncthreads();   // all waves done with sK buffers before epilogue reuse

    // ---- epilogue: combine key-half partials (wh=1 publishes via LDS) ----
    // slab rg gets 16 rows x 128 f32 = 8 KB: slabs 0,16 in sKa; 32,48 in sKb_
    float* sOw = (rg < 32) ? ((float*)sKa + (rg & 16) * 128)
                           : ((float*)sKb_ + (rg & 16) * 128);
    if (wh == 1) {
        #pragma unroll
        for (int r = 0; r < 4; ++r) {
            int lrow = quad * 4 + r;
            #pragma unroll
            for (int dt = 0; dt < 8; ++dt)
                sOw[lrow * 128 + dt * 16 + l15] = acc[dt][r];
            if (l15 == 0) sLp[rg + lrow] = lacc[r];
        }
    }
    __syncthreads();
    if (wh == 0) {
        float* Og = O + ((size_t)b * LQ_ + q0 + rg) * DIM_;
        #pragma unroll
        for (int r = 0; r < 4; ++r) {
            int lrow = quad * 4 + r;
            float inv = 1.0f / (lacc[r] + sLp[rg + lrow]);
            #pragma unroll
            for (int dt = 0; dt < 8; ++dt)
                Og[(size_t)lrow * DIM_ + dt * 16 + l15] =
                    (acc[dt][r] + sOw[lrow * 128 + dt * 16 + l15]) * inv;
        }
    }
}

// ================= fallback (validated R1 kernel, ws too small) =============
#define QS 136
#define VS 72
__global__ __launch_bounds__(NTH, 2) void attn_fallback(
    const float* __restrict__ Q, const float* __restrict__ K,
    const float* __restrict__ V, const float* __restrict__ Mk,
    float* __restrict__ O)
{
    __shared__ __align__(16) unsigned short sQ[64][QS];
    __shared__ __align__(16) unsigned short sK[64][QS];
    __shared__ __align__(16) unsigned short sVt[DIM_][VS];
    __shared__ __align__(16) unsigned short sPf[64][VS];
    __shared__ float sB[64];

    const int tid  = threadIdx.x;
    const int w    = tid >> 6, lane = tid & 63;
    const int quad = lane >> 4, l15 = lane & 15;
    const int bid = blockIdx.x;
    const int grp = bid >> 3;
    const int b   = (bid & 7) + 8 * (grp & 1);
    const int q0  = (grp >> 1) * 64;

    {
        const float4* Qg = (const float4*)(Q + ((size_t)b * LQ_ + q0) * DIM_);
        #pragma unroll
        for (int it = 0; it < 8; ++it) {
            int i = tid + it * NTH;
            int r = i >> 5, c4 = i & 31;
            float4 v = Qg[r * 32 + c4];
            ushort4 h = { f2bf(v.x), f2bf(v.y), f2bf(v.z), f2bf(v.w) };
            *(ushort4*)&sQ[r][c4 * 4] = h;
        }
    }
    __syncthreads();
    bf16x8 aQ[4];
    #pragma unroll
    for (int ks = 0; ks < 4; ++ks)
        aQ[ks] = *(const bf16x8*)&sQ[w * 16 + l15][ks * 32 + quad * 8];

    float m_i[4], l_i[4];
    f32x4 acc[8];
    #pragma unroll
    for (int r = 0; r < 4; ++r) { m_i[r] = -3.0e38f; l_i[r] = 0.f; }
    #pragma unroll
    for (int dt = 0; dt < 8; ++dt) acc[dt] = (f32x4){0.f, 0.f, 0.f, 0.f};

    for (int k0 = 0; k0 < LK_; k0 += 64) {
        const float4* Kg = (const float4*)(K + ((size_t)b * LK_ + k0) * DIM_);
        const float4* Vg = (const float4*)(V + ((size_t)b * LK_ + k0) * DIM_);
        #pragma unroll
        for (int it = 0; it < 8; ++it) {
            int i = tid + it * NTH;
            int r = i >> 5, c4 = i & 31;
            float4 kv = Kg[r * 32 + c4];
            ushort4 h = { f2bf(kv.x), f2bf(kv.y), f2bf(kv.z), f2bf(kv.w) };
            *(ushort4*)&sK[r][c4 * 4] = h;
            float4 vv = Vg[r * 32 + c4];
            int d = c4 * 4;
            sVt[d + 0][r] = f2bf(vv.x);
            sVt[d + 1][r] = f2bf(vv.y);
            sVt[d + 2][r] = f2bf(vv.z);
            sVt[d + 3][r] = f2bf(vv.w);
        }
        if (tid < 64) sB[tid] = Mk[k0 + tid] * NEGBIG;
        __syncthreads();

        f32x4 s[4];
        #pragma unroll
        for (int kt = 0; kt < 4; ++kt) {
            f32x4 c = (f32x4){0.f, 0.f, 0.f, 0.f};
            #pragma unroll
            for (int ks = 0; ks < 4; ++ks) {
                bf16x8 bk = *(const bf16x8*)&sK[kt * 16 + l15][ks * 32 + quad * 8];
                c = __builtin_amdgcn_mfma_f32_16x16x32_bf16(aQ[ks], bk, c, 0, 0, 0);
            }
            float bias = sB[kt * 16 + l15];
            #pragma unroll
            for (int r = 0; r < 4; ++r) s[kt][r] = c[r] * SCALE_ + bias;
        }
        #pragma unroll
        for (int r = 0; r < 4; ++r) {
            float mx = fmaxf(fmaxf(s[0][r], s[1][r]), fmaxf(s[2][r], s[3][r]));
            #pragma unroll
            for (int off = 1; off < 16; off <<= 1) mx = fmaxf(mx, __shfl_xor(mx, off));
            float mn = fmaxf(m_i[r], mx);
            float al = __expf(m_i[r] - mn);
            m_i[r] = mn;
            float rsum = 0.f;
            #pragma unroll
            for (int kt = 0; kt < 4; ++kt) {
                float p = __expf(s[kt][r] - mn);
                rsum += p;
                sPf[w * 16 + quad * 4 + r][kt * 16 + l15] = f2bf(p);
            }
            #pragma unroll
            for (int off = 1; off < 16; off <<= 1) rsum += __shfl_xor(rsum, off);
            l_i[r] = l_i[r] * al + rsum;
            #pragma unroll
            for (int dt = 0; dt < 8; ++dt) acc[dt][r] *= al;
        }
        bf16x8 aP0 = *(const bf16x8*)&sPf[w * 16 + l15][quad * 8];
        bf16x8 aP1 = *(const bf16x8*)&sPf[w * 16 + l15][32 + quad * 8];
        #pragma unroll
        for (int dt = 0; dt < 8; ++dt) {
            bf16x8 bv0 = *(const bf16x8*)&sVt[dt * 16 + l15][quad * 8];
            bf16x8 bv1 = *(const bf16x8*)&sVt[dt * 16 + l15][32 + quad * 8];
            acc[dt] = __builtin_amdgcn_mfma_f32_16x16x32_bf16(aP0, bv0, acc[dt], 0, 0, 0);
            acc[dt] = __builtin_amdgcn_mfma_f32_16x16x32_bf16(aP1, bv1, acc[dt], 0, 0, 0);
        }
        __syncthreads();
    }
    float* Og = O + ((size_t)b * LQ_ + q0 + w * 16) * DIM_;
    #pragma unroll
    for (int r = 0; r < 4; ++r) {
        float inv = 1.0f / l_i[r];
        int row = quad * 4 + r;
        #pragma unroll
        for (int dt = 0; dt < 8; ++dt)
            Og[(size_t)row * DIM_ + dt * 16 + l15] = acc[dt][r] * inv;
    }
}

extern "C" void kernel_launch(void* const* d_in, const int* in_sizes, int n_in,
                              void* d_out, int out_size, void* d_ws, size_t ws_size,
                              hipStream_t stream)
{
    const float* Q  = (const float*)d_in[0];
    const float* K  = (const float*)d_in[1];
    const float* V  = (const float*)d_in[2];
    const float* Mk = (const float*)d_in[3];
    float* O = (float*)d_out;

    const size_t seg  = (size_t)B_ * LK_ * DIM_ * 2;   // 8 MB per packed tensor
    const size_t need = 16384 + 2 * seg;               // hdr+idx + Kb + Vtb
    if (ws_size >= need) {
        int* hdr = (int*)d_ws;                          // [0] = kept count
        int* idx = hdr + 16;                            // 2048 ints
        unsigned short* Kb  = (unsigned short*)((char*)d_ws + 16384);
        unsigned short* Vtb = Kb + seg / 2;
        hipLaunchKernelGGL(build_idx, dim3(1),    dim3(256), 0, stream, Mk, hdr, idx);
        hipLaunchKernelGGL(pack_kv,   dim3(2560), dim3(NTH), 0, stream, K, V, hdr, idx, Kb, Vtb);
        hipLaunchKernelGGL(attn_mfma8, dim3(512), dim3(ATH), 0, stream, Q, Kb, Vtb, hdr, O);
    } else {
        hipLaunchKernelGGL(attn_fallback, dim3(512), dim3(NTH), 0, stream, Q, K, V, Mk, O);
    }
}

// Round 8
// 144.597 us; speedup vs baseline: 1.3014x; 1.3014x over previous
//
#include <hip/hip_runtime.h>
#include <hip/hip_bf16.h>

// R7 baseline resubmit (infra-vs-source probe after 3 failed R12 runs).
// Byte-identical to the Round-0 kernel that measured 143.7 us (passed).
// R7: bf16-MFMA flash attention; V served from global (no V LDS buffers).
// - K: masked-key-compacted, key-interleaved, XOR-swizzled bf16 tiles in ws,
//   double-buffered in LDS via global_load_lds (R6 pipeline).
// - V: packed V^T tiles laid out so each PV B-frag is 16 contiguous bytes;
//   bv loaded global->VGPR (1KB coalesced/inst, L2-hot). LDS 75->42 KB,
//   LDS pipe traffic ~2400->~1400 cyc/CU-iter.
// - exp2 via __builtin_amdgcn_exp2f; fixed-max shift dropped (cancels in
//   normalization): s = kept ? qk : -1e30 (cndmask), p = exp2(s).

#define B_    16
#define LQ_   2048
#define LK_   2048
#define DIM_  128
#define NTH   256
#define SCALE_ 0.08838834764831845f          // 1/sqrt(128)
#define LOG2E_ 1.4426950408889634f
#define SC2_   (SCALE_ * LOG2E_)
#define NEGBIG -1.0e9f
#define PS 72                                 // sP row stride (ushorts)

typedef __attribute__((ext_vector_type(8))) short bf16x8;
typedef __attribute__((ext_vector_type(4))) float f32x4;

#define GLDS(gsrc, ldst) \
  __builtin_amdgcn_global_load_lds( \
      (const __attribute__((address_space(1))) unsigned int*)(gsrc), \
      (__attribute__((address_space(3))) unsigned int*)(ldst), 16, 0, 0)

static __device__ __forceinline__ unsigned short f2bf(float f) {
    unsigned int u = __builtin_bit_cast(unsigned int, f);
    u += 0x7fff + ((u >> 16) & 1);          // RNE
    return (unsigned short)(u >> 16);
}

// ---- kernel 1: kept-key index list (mask==0 kept), 1 block ----
__global__ __launch_bounds__(256) void build_idx(const float* __restrict__ Mk,
                                                 int* __restrict__ hdr,
                                                 int* __restrict__ idx)
{
    __shared__ int sc[256];
    int t = threadIdx.x;
    int keep[8], loc[8];
    int c = 0;
    #pragma unroll
    for (int j = 0; j < 8; ++j) {
        keep[j] = (Mk[t * 8 + j] < 0.5f) ? 1 : 0;
        loc[j] = c;
        c += keep[j];
    }
    sc[t] = c;
    __syncthreads();
    for (int off = 1; off < 256; off <<= 1) {
        int v = (t >= off) ? sc[t - off] : 0;
        __syncthreads();
        sc[t] += v;
        __syncthreads();
    }
    int base = sc[t] - c;
    #pragma unroll
    for (int j = 0; j < 8; ++j)
        if (keep[j]) idx[base + loc[j]] = t * 8 + j;
    if (t == 255) hdr[0] = sc[255];
}

// ---- kernel 2: gather-pack kept K rows (key-interleaved, chunk^row swizzle)
//      + V^T tiles: layout off = kc*4096 + d*32 + (c&3)*8 (kc = key-half),
//      so PV frag (16 rows x 16B) is 1KB contiguous per instruction. ----
__global__ __launch_bounds__(NTH) void pack_kv(
    const float* __restrict__ K, const float* __restrict__ V,
    const int* __restrict__ hdr, const int* __restrict__ idx,
    unsigned short* __restrict__ Kb, unsigned short* __restrict__ Vtb)
{
    const int cnt = hdr[0];
    int bid = blockIdx.x;
    if (bid < 2048) {
        int gid = bid * NTH + threadIdx.x;     // granule = 8 floats (1 chunk)
        int c  = gid & 15;
        int r2 = (gid >> 4) & 63;              // packed (interleaved) row
        int T  = gid >> 10;                    // batch*32 + tile
        int slot = (r2 & 32) + 2 * (r2 & 15) + ((r2 >> 4) & 1);
        int j = (T & 31) * 64 + slot;
        int key = (j < cnt) ? idx[j] : 0;
        const float4* s4 = (const float4*)(K + ((size_t)(T >> 5) * LK_ + key) * DIM_ + c * 8);
        float4 a = s4[0], bq = s4[1];
        bf16x8 h = { (short)f2bf(a.x),  (short)f2bf(a.y),  (short)f2bf(a.z),  (short)f2bf(a.w),
                     (short)f2bf(bq.x), (short)f2bf(bq.y), (short)f2bf(bq.z), (short)f2bf(bq.w) };
        *(bf16x8*)(Kb + (size_t)T * 8192 + r2 * 128 + ((c ^ (r2 & 15)) * 8)) = h;
    } else {
        int T = bid - 2048;                    // batch*32 + tile
        int w4 = threadIdx.x >> 6, lane = threadIdx.x & 63;
        const float* vb = V + (size_t)(T >> 5) * LK_ * DIM_;
        const int* ix = idx + (T & 31) * 64;
        int jbase = (T & 31) * 64;
        unsigned short* db = Vtb + (size_t)T * 8192;
        #pragma unroll
        for (int half = 0; half < 2; ++half) {
            int d = half * 64 + lane;
            #pragma unroll
            for (int cb = 0; cb < 8; cb += 4) {
                int c = cb + w4;               // chunk of 8 keys, c in 0..7
                float v[8];
                #pragma unroll
                for (int kk = 0; kk < 8; ++kk) {
                    int j = c * 8 + kk;
                    int key = (jbase + j < cnt) ? ix[j] : 0;
                    v[kk] = vb[(size_t)key * DIM_ + d];   // coalesced over lanes (d)
                }
                bf16x8 h = { (short)f2bf(v[0]), (short)f2bf(v[1]), (short)f2bf(v[2]), (short)f2bf(v[3]),
                             (short)f2bf(v[4]), (short)f2bf(v[5]), (short)f2bf(v[6]), (short)f2bf(v[7]) };
                *(bf16x8*)(db + (c >> 2) * 4096 + d * 32 + (c & 3) * 8) = h;
            }
        }
    }
}

// ---- main kernel ----
__global__ __launch_bounds__(NTH, 2) void attn_mfma6(
    const float* __restrict__ Q, const unsigned short* __restrict__ Kb,
    const unsigned short* __restrict__ Vtb, const int* __restrict__ hdr,
    float* __restrict__ O)
{
    __shared__ __align__(16) unsigned short sKa[8192];     // 16 KB
    __shared__ __align__(16) unsigned short sKb_[8192];    // 16 KB
    __shared__ __align__(16) unsigned short sP[64 * PS];   // 9.2 KB, also Q staging
    __shared__ float sLp[64];

    const int tid  = threadIdx.x;
    const int w    = tid >> 6, lane = tid & 63;
    const int quad = lane >> 4, l15 = lane & 15;
    const int rg   = (w & 1) * 32;     // row group base
    const int wh   = w >> 1;           // key half
    const int kh   = wh * 32;

    const int bid = blockIdx.x;
    const int grp = bid >> 3;
    const int b   = (bid & 7) + 8 * (grp & 1);   // XCD-aware
    const int q0  = (grp >> 1) * 64;

    const int cnt = hdr[0];
    const int nIter2 = (((cnt + 63) >> 6) + 1) & ~1;   // even # of 64-key tiles

    bf16x8 vone;
    #pragma unroll
    for (int j = 0; j < 8; ++j) vone[j] = (short)0x3F80;

    // per-lane V-frag base offset (ushorts) within a tile
    const int voff = wh * 4096 + l15 * 32 + quad * 8;

    // ---- stage Q (pre-scaled by SC2_) in two 32-row halves through sP ----
    bf16x8 aQ[2][4];
    {
        const float4* Qg = (const float4*)(Q + ((size_t)b * LQ_ + q0) * DIM_);
        #pragma unroll
        for (int h = 0; h < 2; ++h) {
            #pragma unroll
            for (int it = 0; it < 4; ++it) {
                int i2 = tid + it * NTH;
                int r = i2 >> 5, c4 = i2 & 31;
                float4 v = Qg[(h * 32 + r) * 32 + c4];
                ushort4 hh = { f2bf(v.x * SC2_), f2bf(v.y * SC2_),
                               f2bf(v.z * SC2_), f2bf(v.w * SC2_) };
                *(ushort4*)&sP[r * 128 + (((c4 >> 1) ^ (r & 15)) * 8) + (c4 & 1) * 4] = hh;
            }
            __syncthreads();
            if ((rg >> 5) == h) {
                #pragma unroll
                for (int rs = 0; rs < 2; ++rs)
                    #pragma unroll
                    for (int ks = 0; ks < 4; ++ks)
                        aQ[rs][ks] = *(const bf16x8*)&sP[(rs * 16 + l15) * 128 +
                                                         (((ks * 4 + quad) ^ l15) * 8)];
            }
            __syncthreads();
        }
    }

    // ---- prefetch K tile 0 into buffer A ----
    {
        const char* ksrc = (const char*)Kb + (size_t)(b * 32) * 16384;
        #pragma unroll
        for (int j = 0; j < 4; ++j) {
            int o = (j * 4 + w) * 1024;
            GLDS(ksrc + o + lane * 16, (char*)sKa + o);
        }
    }
    __syncthreads();

    f32x4 acc[2][8], lacc[2];
    #pragma unroll
    for (int rs = 0; rs < 2; ++rs) {
        lacc[rs] = (f32x4){0.f, 0.f, 0.f, 0.f};
        #pragma unroll
        for (int dt = 0; dt < 8; ++dt) acc[rs][dt] = (f32x4){0.f, 0.f, 0.f, 0.f};
    }

#define TILE_BODY(CURK, NXTK, I) do {                                          \
    /* V fragments for THIS tile: global->VGPR, fully coalesced, L2-hot */     \
    const unsigned short* vsrc = Vtb + (size_t)(b * 32 + (I)) * 8192 + voff;   \
    bf16x8 bv[8];                                                              \
    _Pragma("unroll")                                                          \
    for (int dt = 0; dt < 8; ++dt) bv[dt] = *(const bf16x8*)(vsrc + dt * 512); \
    const int nxt = (I) + 1;                                                   \
    if (nxt < nIter2) {                                                        \
        const char* ksrc = (const char*)Kb + (size_t)(b * 32 + nxt) * 16384;   \
        _Pragma("unroll")                                                      \
        for (int j = 0; j < 4; ++j) {                                          \
            int o = (j * 4 + w) * 1024;                                        \
            GLDS(ksrc + o + lane * 16, (char*)(NXTK) + o);                     \
        }                                                                      \
    }                                                                          \
    f32x4 s_[2][2];                                                            \
    _Pragma("unroll")                                                          \
    for (int kt2 = 0; kt2 < 2; ++kt2) {                                        \
        f32x4 c0 = (f32x4){0.f,0.f,0.f,0.f}, c1 = (f32x4){0.f,0.f,0.f,0.f};   \
        _Pragma("unroll")                                                      \
        for (int ks = 0; ks < 4; ++ks) {                                       \
            bf16x8 bk = *(const bf16x8*)&(CURK)[(kh + kt2 * 16 + l15) * 128 +  \
                                                (((ks * 4 + quad) ^ l15) * 8)];\
            c0 = __builtin_amdgcn_mfma_f32_16x16x32_bf16(aQ[0][ks], bk, c0, 0,0,0); \
            c1 = __builtin_amdgcn_mfma_f32_16x16x32_bf16(aQ[1][ks], bk, c1, 0,0,0); \
        }                                                                      \
        int slot = (I) * 64 + kh + 2 * l15 + kt2;                              \
        bool kept = slot < cnt;                                                \
        _Pragma("unroll")                                                      \
        for (int r = 0; r < 4; ++r) {                                          \
            s_[0][kt2][r] = kept ? c0[r] : -1.0e30f;                           \
            s_[1][kt2][r] = kept ? c1[r] : -1.0e30f;                           \
        }                                                                      \
    }                                                                          \
    _Pragma("unroll")                                                          \
    for (int rs = 0; rs < 2; ++rs)                                             \
        _Pragma("unroll")                                                      \
        for (int r = 0; r < 4; ++r) {                                          \
            float p0 = __builtin_amdgcn_exp2f(s_[rs][0][r]);                   \
            float p1 = __builtin_amdgcn_exp2f(s_[rs][1][r]);                   \
            int row = rg + rs * 16 + quad * 4 + r;                             \
            unsigned pk = __builtin_amdgcn_perm(                               \
                __builtin_bit_cast(unsigned, p1),                              \
                __builtin_bit_cast(unsigned, p0), 0x07060302u);                \
            *(unsigned*)&sP[row * PS + kh + 2 * l15] = pk;                     \
        }                                                                      \
    {                                                                          \
        bf16x8 aP0 = *(const bf16x8*)&sP[(rg + l15) * PS + kh + quad * 8];     \
        bf16x8 aP1 = *(const bf16x8*)&sP[(rg + 16 + l15) * PS + kh + quad * 8];\
        lacc[0] = __builtin_amdgcn_mfma_f32_16x16x32_bf16(aP0, vone, lacc[0], 0,0,0); \
        lacc[1] = __builtin_amdgcn_mfma_f32_16x16x32_bf16(aP1, vone, lacc[1], 0,0,0); \
        _Pragma("unroll")                                                      \
        for (int dt = 0; dt < 8; ++dt) {                                       \
            acc[0][dt] = __builtin_amdgcn_mfma_f32_16x16x32_bf16(aP0, bv[dt], acc[0][dt], 0,0,0); \
            acc[1][dt] = __builtin_amdgcn_mfma_f32_16x16x32_bf16(aP1, bv[dt], acc[1][dt], 0,0,0); \
        }                                                                      \
    }                                                                          \
    __syncthreads();                                                           \
} while (0)

    for (int kk = 0; kk < nIter2; kk += 2) {
        TILE_BODY(sKa,  sKb_, kk);
        TILE_BODY(sKb_, sKa,  kk + 1);
    }
#undef TILE_BODY

    // ---- epilogue: combine key-half partials (wh=1 publishes via LDS) ----
    float* sOw = (rg == 0) ? (float*)sKa : (float*)sKb_;   // 32 rows x 128 f32
    if (wh == 1) {
        #pragma unroll
        for (int rs = 0; rs < 2; ++rs)
            #pragma unroll
            for (int r = 0; r < 4; ++r) {
                int lrow = rs * 16 + quad * 4 + r;
                #pragma unroll
                for (int dt = 0; dt < 8; ++dt)
                    sOw[lrow * 128 + dt * 16 + l15] = acc[rs][dt][r];
                if (l15 == 0) sLp[rg + lrow] = lacc[rs][r];
            }
    }
    __syncthreads();
    if (wh == 0) {
        float* Og = O + ((size_t)b * LQ_ + q0 + rg) * DIM_;
        #pragma unroll
        for (int rs = 0; rs < 2; ++rs)
            #pragma unroll
            for (int r = 0; r < 4; ++r) {
                int lrow = rs * 16 + quad * 4 + r;
                float inv = 1.0f / (lacc[rs][r] + sLp[rg + lrow]);
                #pragma unroll
                for (int dt = 0; dt < 8; ++dt)
                    Og[(size_t)lrow * DIM_ + dt * 16 + l15] =
                        (acc[rs][dt][r] + sOw[lrow * 128 + dt * 16 + l15]) * inv;
            }
    }
}

// ================= fallback (validated R1 kernel, ws too small) =============
#define QS 136
#define VS 72
__global__ __launch_bounds__(NTH, 2) void attn_fallback(
    const float* __restrict__ Q, const float* __restrict__ K,
    const float* __restrict__ V, const float* __restrict__ Mk,
    float* __restrict__ O)
{
    __shared__ __align__(16) unsigned short sQ[64][QS];
    __shared__ __align__(16) unsigned short sK[64][QS];
    __shared__ __align__(16) unsigned short sVt[DIM_][VS];
    __shared__ __align__(16) unsigned short sPf[64][VS];
    __shared__ float sB[64];

    const int tid  = threadIdx.x;
    const int w    = tid >> 6, lane = tid & 63;
    const int quad = lane >> 4, l15 = lane & 15;
    const int bid = blockIdx.x;
    const int grp = bid >> 3;
    const int b   = (bid & 7) + 8 * (grp & 1);
    const int q0  = (grp >> 1) * 64;

    {
        const float4* Qg = (const float4*)(Q + ((size_t)b * LQ_ + q0) * DIM_);
        #pragma unroll
        for (int it = 0; it < 8; ++it) {
            int i = tid + it * NTH;
            int r = i >> 5, c4 = i & 31;
            float4 v = Qg[r * 32 + c4];
            ushort4 h = { f2bf(v.x), f2bf(v.y), f2bf(v.z), f2bf(v.w) };
            *(ushort4*)&sQ[r][c4 * 4] = h;
        }
    }
    __syncthreads();
    bf16x8 aQ[4];
    #pragma unroll
    for (int ks = 0; ks < 4; ++ks)
        aQ[ks] = *(const bf16x8*)&sQ[w * 16 + l15][ks * 32 + quad * 8];

    float m_i[4], l_i[4];
    f32x4 acc[8];
    #pragma unroll
    for (int r = 0; r < 4; ++r) { m_i[r] = -3.0e38f; l_i[r] = 0.f; }
    #pragma unroll
    for (int dt = 0; dt < 8; ++dt) acc[dt] = (f32x4){0.f, 0.f, 0.f, 0.f};

    for (int k0 = 0; k0 < LK_; k0 += 64) {
        const float4* Kg = (const float4*)(K + ((size_t)b * LK_ + k0) * DIM_);
        const float4* Vg = (const float4*)(V + ((size_t)b * LK_ + k0) * DIM_);
        #pragma unroll
        for (int it = 0; it < 8; ++it) {
            int i = tid + it * NTH;
            int r = i >> 5, c4 = i & 31;
            float4 kv = Kg[r * 32 + c4];
            ushort4 h = { f2bf(kv.x), f2bf(kv.y), f2bf(kv.z), f2bf(kv.w) };
            *(ushort4*)&sK[r][c4 * 4] = h;
            float4 vv = Vg[r * 32 + c4];
            int d = c4 * 4;
            sVt[d + 0][r] = f2bf(vv.x);
            sVt[d + 1][r] = f2bf(vv.y);
            sVt[d + 2][r] = f2bf(vv.z);
            sVt[d + 3][r] = f2bf(vv.w);
        }
        if (tid < 64) sB[tid] = Mk[k0 + tid] * NEGBIG;
        __syncthreads();

        f32x4 s[4];
        #pragma unroll
        for (int kt = 0; kt < 4; ++kt) {
            f32x4 c = (f32x4){0.f, 0.f, 0.f, 0.f};
            #pragma unroll
            for (int ks = 0; ks < 4; ++ks) {
                bf16x8 bk = *(const bf16x8*)&sK[kt * 16 + l15][ks * 32 + quad * 8];
                c = __builtin_amdgcn_mfma_f32_16x16x32_bf16(aQ[ks], bk, c, 0, 0, 0);
            }
            float bias = sB[kt * 16 + l15];
            #pragma unroll
            for (int r = 0; r < 4; ++r) s[kt][r] = c[r] * SCALE_ + bias;
        }
        #pragma unroll
        for (int r = 0; r < 4; ++r) {
            float mx = fmaxf(fmaxf(s[0][r], s[1][r]), fmaxf(s[2][r], s[3][r]));
            #pragma unroll
            for (int off = 1; off < 16; off <<= 1) mx = fmaxf(mx, __shfl_xor(mx, off));
            float mn = fmaxf(m_i[r], mx);
            float al = __expf(m_i[r] - mn);
            m_i[r] = mn;
            float rsum = 0.f;
            #pragma unroll
            for (int kt = 0; kt < 4; ++kt) {
                float p = __expf(s[kt][r] - mn);
                rsum += p;
                sPf[w * 16 + quad * 4 + r][kt * 16 + l15] = f2bf(p);
            }
            #pragma unroll
            for (int off = 1; off < 16; off <<= 1) rsum += __shfl_xor(rsum, off);
            l_i[r] = l_i[r] * al + rsum;
            #pragma unroll
            for (int dt = 0; dt < 8; ++dt) acc[dt][r] *= al;
        }
        bf16x8 aP0 = *(const bf16x8*)&sPf[w * 16 + l15][quad * 8];
        bf16x8 aP1 = *(const bf16x8*)&sPf[w * 16 + l15][32 + quad * 8];
        #pragma unroll
        for (int dt = 0; dt < 8; ++dt) {
            bf16x8 bv0 = *(const bf16x8*)&sVt[dt * 16 + l15][quad * 8];
            bf16x8 bv1 = *(const bf16x8*)&sVt[dt * 16 + l15][32 + quad * 8];
            acc[dt] = __builtin_amdgcn_mfma_f32_16x16x32_bf16(aP0, bv0, acc[dt], 0, 0, 0);
            acc[dt] = __builtin_amdgcn_mfma_f32_16x16x32_bf16(aP1, bv1, acc[dt], 0, 0, 0);
        }
        __syncthreads();
    }
    float* Og = O + ((size_t)b * LQ_ + q0 + w * 16) * DIM_;
    #pragma unroll
    for (int r = 0; r < 4; ++r) {
        float inv = 1.0f / l_i[r];
        int row = quad * 4 + r;
        #pragma unroll
        for (int dt = 0; dt < 8; ++dt)
            Og[(size_t)row * DIM_ + dt * 16 + l15] = acc[dt][r] * inv;
    }
}

extern "C" void kernel_launch(void* const* d_in, const int* in_sizes, int n_in,
                              void* d_out, int out_size, void* d_ws, size_t ws_size,
                              hipStream_t stream)
{
    const float* Q  = (const float*)d_in[0];
    const float* K  = (const float*)d_in[1];
    const float* V  = (const float*)d_in[2];
    const float* Mk = (const float*)d_in[3];
    float* O = (float*)d_out;

    const size_t seg  = (size_t)B_ * LK_ * DIM_ * 2;   // 8 MB per packed tensor
    const size_t need = 16384 + 2 * seg;               // hdr+idx + Kb + Vtb
    if (ws_size >= need) {
        int* hdr = (int*)d_ws;                          // [0] = kept count
        int* idx = hdr + 16;                            // 2048 ints
        unsigned short* Kb  = (unsigned short*)((char*)d_ws + 16384);
        unsigned short* Vtb = Kb + seg / 2;
        hipLaunchKernelGGL(build_idx, dim3(1),    dim3(256), 0, stream, Mk, hdr, idx);
        hipLaunchKernelGGL(pack_kv,   dim3(2560), dim3(NTH), 0, stream, K, V, hdr, idx, Kb, Vtb);
        hipLaunchKernelGGL(attn_mfma6, dim3(512), dim3(NTH), 0, stream, Q, Kb, Vtb, hdr, O);
    } else {
        hipLaunchKernelGGL(attn_fallback, dim3(512), dim3(NTH), 0, stream, Q, K, V, Mk, O);
    }
}